// Round 13
// baseline (33562.427 us; speedup 1.0000x reference)
//
#include <hip/hip_runtime.h>
#include <cstdint>

#define T_STEPS 8192
#define HDIM    1024
#define NBLK    256

typedef float        f32x4 __attribute__((ext_vector_type(4)));
typedef unsigned int u32x4 __attribute__((ext_vector_type(4)));

__device__ __forceinline__ float dot4(f32x4 a, f32x4 b) {
    return a[0] * b[0] + a[1] * b[1] + a[2] * b[2] + a[3] * b[3];
}
__device__ __forceinline__ float sigmoidf_(float v) { return 1.0f / (1.0f + __expf(-v)); }
__device__ __forceinline__ float tanhf_(float v)    { return 1.0f - 2.0f / (__expf(2.0f * v) + 1.0f); }
__device__ __forceinline__ unsigned bf16_rne(float f) {
    unsigned b = __float_as_uint(f);
    return (b + 0x7FFFu + ((b >> 16) & 1u)) >> 16;
}

// raw barrier: LDS visibility only (lgkmcnt), vmcnt NOT drained — prefetches
// stay in flight across steps (the __syncthreads vmcnt(0) drain was eating
// ~900cy/step of x-prefetch latency in R1-R12).
#define BAR() do {                                            \
    asm volatile("s_waitcnt lgkmcnt(0)" ::: "memory");        \
    __builtin_amdgcn_sched_barrier(0);                        \
    __builtin_amdgcn_s_barrier();                             \
    __builtin_amdgcn_sched_barrier(0);                        \
} while (0)

// 256 blocks x 512 threads (8 waves, 2/SIMD). K-split: wave w owns unit
// r=w&3, K-half hh=w>>2 (elements 4l + 512*hh + 256*i, i=0,1).
// Per-wave weights = 64 VGPR (whh-half 32 + wih-half 32) -> ~120 total,
// fits the allocator's ~128 budget WITHOUT pins (R1-R12: 128-reg arrays
// never stay resident). Waves 0-3: combine partials, gates, publish
// (R8's writer-private ring, byte-identical). Waves 4-7: poll (R8's
// thread-tid mapping) OVERLAPPED with gate compute; x-prefetch issued
// after detect so the poll vmcnt(0) stays clean. out -> block-contiguous
// staging (kills the 5x cross-CU partial-line RMW on out), final
// transpose kernel rearranges.
__global__ __launch_bounds__(512, 2)
void lstm_persistent(const float* __restrict__ x,
                     const float* __restrict__ W_ih,
                     const float* __restrict__ W_hh,
                     const float* __restrict__ b_ih,
                     const float* __restrict__ b_hh,
                     const float* __restrict__ h0,
                     const float* __restrict__ c0,
                     float* __restrict__ stag,
                     unsigned int* __restrict__ ring)
{
    __shared__ float h_lds[2][HDIM];
    __shared__ float p_lds[4][4];     // partner partials [unit r][gate q]

    const int tid = threadIdx.x;
    const int w   = tid >> 6;         // wave 0..7
    const int l   = tid & 63;         // lane
    const int r   = w & 3;            // unit_local
    const int hh  = w >> 2;           // K-half
    const int u   = (blockIdx.x << 2) + r;
    const int koff = 4 * l + 512 * hh;

    // ---- weight halves: 16 x f32x4 = 64 VGPRs per wave ----
    f32x4 whh[8], wih[8];
#pragma unroll
    for (int q = 0; q < 4; ++q) {
        const float* rh = W_hh + (size_t)(q * HDIM + u) * HDIM + koff;
        const float* ri = W_ih + (size_t)(q * HDIM + u) * HDIM + koff;
        whh[q * 2 + 0] = *(const f32x4*)(rh);
        whh[q * 2 + 1] = *(const f32x4*)(rh + 256);
        wih[q * 2 + 0] = *(const f32x4*)(ri);
        wih[q * 2 + 1] = *(const f32x4*)(ri + 256);
    }

    float bias[4] = {};
    float c = 0.f;
    if (w < 4) {
#pragma unroll
        for (int q = 0; q < 4; ++q) bias[q] = b_ih[q * HDIM + u] + b_hh[q * HDIM + u];
        c = c0[u];
    }

    f32x4 hrh[2];
    hrh[0] = *(const f32x4*)(h0 + koff);
    hrh[1] = *(const f32x4*)(h0 + koff + 256);

    // x pipeline (halves): gxpp = wih-half partials for step t; xrh = x[t+1]
    float gxpp[4];
    {
        f32x4 x0h0 = *(const f32x4*)(x + koff);
        f32x4 x0h1 = *(const f32x4*)(x + koff + 256);
#pragma unroll
        for (int q = 0; q < 4; ++q)
            gxpp[q] = dot4(wih[q * 2], x0h0) + dot4(wih[q * 2 + 1], x0h1);
    }
    f32x4 xrh[2], xnh[2];
    xrh[0] = *(const f32x4*)(x + HDIM + koff);
    xrh[1] = *(const f32x4*)(x + HDIM + koff + 256);

    float* stagb = stag + (size_t)blockIdx.x * T_STEPS * 4;

    for (int t = 0; t < T_STEPS; ++t) {
        // ---- phase A (all waves): half-K matvec partial + wave reduce ----
        float acc[4];
#pragma unroll
        for (int q = 0; q < 4; ++q)
            acc[q] = gxpp[q] + dot4(whh[q * 2], hrh[0]) + dot4(whh[q * 2 + 1], hrh[1]);
#pragma unroll
        for (int m = 1; m < 64; m <<= 1) {
#pragma unroll
            for (int q = 0; q < 4; ++q) acc[q] += __shfl_xor(acc[q], m, 64);
        }
        if (w >= 4 && l == 0) {
            f32x4 pv; pv[0] = acc[0]; pv[1] = acc[1]; pv[2] = acc[2]; pv[3] = acc[3];
            *(f32x4*)&p_lds[r][0] = pv;
        }
        BAR();   // barrier1: partials visible

        const int tn = (t + 2 < T_STEPS) ? (t + 2) : (T_STEPS - 1);
        const float* xp = x + (size_t)tn * HDIM + koff;

        if (w < 4) {
            // combine + gates + publish  (runs WHILE waves 4-7 poll)
            const f32x4 part = *(const f32x4*)&p_lds[r][0];   // LDS broadcast
            const float gi = sigmoidf_(acc[0] + part[0] + bias[0]);
            const float gf = sigmoidf_(acc[1] + part[1] + bias[1]);
            const float gg = tanhf_   (acc[2] + part[2] + bias[2]);
            const float go = sigmoidf_(acc[3] + part[3] + bias[3]);
            c = gf * c + gi * gg;
            const float hval = go * tanhf_(c);

            if (l == 0) {
                const unsigned pk = ((unsigned)(t + 1) << 16) | bf16_rne(hval);
                unsigned int* slot =
                    ring + (((t & 1) * NBLK + blockIdx.x) << 4) + r;
                asm volatile("global_store_dword %0, %1, off sc0 sc1"
                             :: "v"((unsigned long long)slot), "v"(pk) : "memory");
            }
            if (l == 1) stagb[t * 4 + r] = hval;   // block-private contiguous

            // x[t+2] prefetch + gxp-next: no poll on this path, acks drain lazily
            xnh[0] = *(const f32x4*)(xp);
            xnh[1] = *(const f32x4*)(xp + 256);
#pragma unroll
            for (int q = 0; q < 4; ++q)
                gxpp[q] = dot4(wih[q * 2], xrh[0]) + dot4(wih[q * 2 + 1], xrh[1]);
        } else {
            // gxp-next FIRST (publishes need ~400cy to land anyway)
#pragma unroll
            for (int q = 0; q < 4; ++q)
                gxpp[q] = dot4(wih[q * 2], xrh[0]) + dot4(wih[q * 2 + 1], xrh[1]);
            if (t < T_STEPS - 1) {
                // poll: thread p = (w-4)*64+l owns block p's private line
                const int p_idx = ((w - 4) << 6) + l;
                const unsigned e = (unsigned)(t + 1);
                const unsigned long long base =
                    (unsigned long long)(ring + (((t & 1) * NBLK + p_idx) << 4));
                u32x4 p;
                for (;;) {
                    // no "memory" clobber (R6-proven): weights stay resident
                    asm volatile(
                        "global_load_dwordx4 %0, %1, off sc0 sc1\n\t"
                        "s_waitcnt vmcnt(0)"
                        : "=&v"(p) : "v"(base));
                    if ((p[0] >> 16) == e && (p[1] >> 16) == e &&
                        (p[2] >> 16) == e && (p[3] >> 16) == e) break;
                }
                const int ns = (t + 1) & 1;
                f32x4 hv;
                hv[0] = __uint_as_float(p[0] << 16);
                hv[1] = __uint_as_float(p[1] << 16);
                hv[2] = __uint_as_float(p[2] << 16);
                hv[3] = __uint_as_float(p[3] << 16);
                *(f32x4*)&h_lds[ns][4 * p_idx] = hv;
                // x prefetch AFTER detect — keeps poll vmcnt scope clean
                xnh[0] = *(const f32x4*)(xp);
                xnh[1] = *(const f32x4*)(xp + 256);
            }
        }
        if (t == T_STEPS - 1) break;
        BAR();   // barrier2: h_lds[ns] visible
        {
            const int ns = (t + 1) & 1;
            hrh[0] = *(const f32x4*)&h_lds[ns][koff];
            hrh[1] = *(const f32x4*)&h_lds[ns][koff + 256];
        }
        xrh[0] = xnh[0]; xrh[1] = xnh[1];
    }
}

// stag[b][t][r] -> out[t][4b+r]; coalesced 16B writes per thread
__global__ __launch_bounds__(256)
void untranspose(const float* __restrict__ stag, float* __restrict__ out)
{
    const int t = blockIdx.x;
    const int b = threadIdx.x;
    f32x4 v = *(const f32x4*)(stag + (size_t)b * T_STEPS * 4 + t * 4);
    *(f32x4*)(out + (size_t)t * HDIM + 4 * b) = v;
}

extern "C" void kernel_launch(void* const* d_in, const int* in_sizes, int n_in,
                              void* d_out, int out_size, void* d_ws, size_t ws_size,
                              hipStream_t stream)
{
    const float* x    = (const float*)d_in[0];
    const float* W_ih = (const float*)d_in[1];
    const float* W_hh = (const float*)d_in[2];
    const float* b_ih = (const float*)d_in[3];
    const float* b_hh = (const float*)d_in[4];
    const float* h0   = (const float*)d_in[5];
    const float* c0   = (const float*)d_in[6];

    unsigned int* ring = (unsigned int*)d_ws;
    float* stag = (float*)((char*)d_ws + (1u << 20));

    hipMemsetAsync(d_ws, 0, 2 * NBLK * 16 * sizeof(unsigned int), stream);
    lstm_persistent<<<NBLK, 512, 0, stream>>>(x, W_ih, W_hh, b_ih, b_hh, h0, c0,
                                              stag, ring);
    untranspose<<<T_STEPS, 256, 0, stream>>>(stag, (float*)d_out);
}

// Round 14
// 26435.284 us; speedup vs baseline: 1.2696x; 1.2696x over previous
//
#include <hip/hip_runtime.h>
#include <cstdint>

#define T_STEPS 8192
#define HDIM    1024
#define NBLK    256
#define NTHR    256

typedef float        f32x4 __attribute__((ext_vector_type(4)));
typedef unsigned int u32x4 __attribute__((ext_vector_type(4)));

__device__ __forceinline__ float dot4(f32x4 a, f32x4 b) {
    return a[0] * b[0] + a[1] * b[1] + a[2] * b[2] + a[3] * b[3];
}
__device__ __forceinline__ float sigmoidf_(float v) { return 1.0f / (1.0f + __expf(-v)); }
__device__ __forceinline__ float tanhf_(float v)    { return 1.0f - 2.0f / (__expf(2.0f * v) + 1.0f); }
__device__ __forceinline__ unsigned bf16_rne(float f) {
    unsigned b = __float_as_uint(f);
    return (b + 0x7FFFu + ((b >> 16) & 1u)) >> 16;
}

// raw barrier: LDS visibility only — vmcnt NOT drained, so the x[t+2]
// prefetch stays in flight across the step boundary (correctness of this
// barrier form proven in R13; __syncthreads' hidden vmcnt(0) was exposing
// ~900cy of HBM latency inside every step in R1-R12).
#define BAR() do {                                            \
    asm volatile("s_waitcnt lgkmcnt(0)" ::: "memory");        \
    __builtin_amdgcn_sched_barrier(0);                        \
    __builtin_amdgcn_s_barrier();                             \
    __builtin_amdgcn_sched_barrier(0);                        \
} while (0)

// R8 (22.3ms, best) with ONLY the detect-path latency restructured:
//  1. poll load ISSUED right after publish (no wait), gxp wih-stream FMAs
//     run as filler between issue and check — poll RT absorbed by work
//  2. x[t+2] HBM prefetch issued AFTER detect — crosses the barrier
//     in-flight (raw BAR), drains inside next step's gxp waits
//  3. raw lgkm-only barrier instead of __syncthreads
// Everything else byte-identical to R8: writer-private ring lines
// (R7: shared lines +50%), (epoch16<<16)|bf16 payload, whh kept/wih
// streamed (the only register shape the allocator accepts, R1-R13).
__global__ __launch_bounds__(NTHR, 1)
void lstm_persistent(const float* __restrict__ x,
                     const float* __restrict__ W_ih,
                     const float* __restrict__ W_hh,
                     const float* __restrict__ b_ih,
                     const float* __restrict__ b_hh,
                     const float* __restrict__ h0,
                     const float* __restrict__ c0,
                     float* __restrict__ out,
                     unsigned int* __restrict__ ring)
{
    __shared__ float h_lds[2][HDIM];

    const int tid = threadIdx.x;
    const int w   = tid >> 6;   // wave 0..3
    const int l   = tid & 63;   // lane
    const int u   = (blockIdx.x << 2) + w;

    // ---- weights: lane l covers elements 4l + 256i (+j) ----
    f32x4 whh[16], wih[16];
#pragma unroll
    for (int q = 0; q < 4; ++q) {
        const float* rh = W_hh + (size_t)(q * HDIM + u) * HDIM + 4 * l;
        const float* ri = W_ih + (size_t)(q * HDIM + u) * HDIM + 4 * l;
#pragma unroll
        for (int i = 0; i < 4; ++i) {
            whh[q * 4 + i] = *(const f32x4*)(rh + 256 * i);
            wih[q * 4 + i] = *(const f32x4*)(ri + 256 * i);
        }
    }
#pragma unroll
    for (int k = 0; k < 16; ++k) {
        asm volatile("" : "+v"(whh[k]));
        asm volatile("" : "+v"(wih[k]));
    }

    float bias[4];
#pragma unroll
    for (int q = 0; q < 4; ++q) bias[q] = b_ih[q * HDIM + u] + b_hh[q * HDIM + u];
    float c = c0[u];  // replicated across the wave

    f32x4 hr[4];
#pragma unroll
    for (int i = 0; i < 4; ++i) hr[i] = *(const f32x4*)(h0 + 4 * l + 256 * i);

    // x pipeline: gxp = Wih partials for step t; xr = x[t+1]; xn = x[t+2]
    float gxp[4];
    {
        f32x4 x0[4];
#pragma unroll
        for (int i = 0; i < 4; ++i) x0[i] = *(const f32x4*)(x + 4 * l + 256 * i);
#pragma unroll
        for (int q = 0; q < 4; ++q) {
            float a = 0.f;
#pragma unroll
            for (int i = 0; i < 4; ++i) a += dot4(wih[q * 4 + i], x0[i]);
            gxp[q] = a;
        }
    }
    f32x4 xr[4], xn[4];
#pragma unroll
    for (int i = 0; i < 4; ++i) xr[i] = *(const f32x4*)(x + HDIM + 4 * l + 256 * i);

    for (int t = 0; t < T_STEPS; ++t) {
        // gates = gxp + Whh . h_{t-1}
        float acc[4];
#pragma unroll
        for (int q = 0; q < 4; ++q) {
            float a = gxp[q];
#pragma unroll
            for (int i = 0; i < 4; ++i) a += dot4(whh[q * 4 + i], hr[i]);
            acc[q] = a;
        }
#pragma unroll
        for (int m = 1; m < 64; m <<= 1) {
#pragma unroll
            for (int q = 0; q < 4; ++q) acc[q] += __shfl_xor(acc[q], m, 64);
        }
        const float gi = sigmoidf_(acc[0] + bias[0]);
        const float gf = sigmoidf_(acc[1] + bias[1]);
        const float gg = tanhf_   (acc[2] + bias[2]);
        const float go = sigmoidf_(acc[3] + bias[3]);
        c = gf * c + gi * gg;
        const float hval = go * tanhf_(c);   // identical on all 64 lanes

        if (l == 0) {
            // publish into this block's private 64B line (R8 layout)
            const unsigned pk = ((unsigned)(t + 1) << 16) | bf16_rne(hval);
            unsigned int* slot = ring + (((t & 1) * NBLK + blockIdx.x) << 4) + w;
            asm volatile("global_store_dword %0, %1, off sc0 sc1"
                         :: "v"((unsigned long long)slot), "v"(pk) : "memory");
            out[(size_t)t * HDIM + u] = hval;
        }
        if (t == T_STEPS - 1) break;

        const unsigned e = (unsigned)(t + 1);
        const unsigned long long base =
            (unsigned long long)(ring + (((t & 1) * NBLK + tid) << 4));

        // ---- issue poll load now (no wait, no clobber) ----
        u32x4 p;
        asm volatile("global_load_dwordx4 %0, %1, off sc0 sc1"
                     : "=v"(p) : "v"(base));

        // filler between issue and check: gxp for t+1 — the wih stream's own
        // vmcnt waits drain the (older) poll load progressively
#pragma unroll
        for (int q = 0; q < 4; ++q) {
            float a = 0.f;
#pragma unroll
            for (int i = 0; i < 4; ++i) a += dot4(wih[q * 4 + i], xr[i]);
            gxp[q] = a;
        }

        // ---- check (rule #18: tie p to the wait, fence the scheduler) ----
        asm volatile("s_waitcnt vmcnt(0)" : "+v"(p) :: "memory");
        __builtin_amdgcn_sched_barrier(0);
        while (!((p[0] >> 16) == e && (p[1] >> 16) == e &&
                 (p[2] >> 16) == e && (p[3] >> 16) == e)) {
            asm volatile(
                "global_load_dwordx4 %0, %1, off sc0 sc1\n\t"
                "s_waitcnt vmcnt(0)"
                : "=&v"(p) : "v"(base) : "memory");
        }

        // x[t+2] prefetch AFTER detect — flies across the raw barrier,
        // drains inside next step's gxp wih-waits (off every critical path)
        {
            const int tn = (t + 2 < T_STEPS) ? (t + 2) : (T_STEPS - 1);
            const float* xp = x + (size_t)tn * HDIM;
#pragma unroll
            for (int i = 0; i < 4; ++i) xn[i] = *(const f32x4*)(xp + 4 * l + 256 * i);
        }
        {
            const int ns = (t + 1) & 1;
            f32x4 hv;
            hv[0] = __uint_as_float(p[0] << 16);
            hv[1] = __uint_as_float(p[1] << 16);
            hv[2] = __uint_as_float(p[2] << 16);
            hv[3] = __uint_as_float(p[3] << 16);
            *(f32x4*)&h_lds[ns][4 * tid] = hv;   // units 4*tid .. 4*tid+3
        }
        BAR();   // lgkm-only: h_lds visible, xn stays in flight
        {
            const int ns = (t + 1) & 1;
#pragma unroll
            for (int i = 0; i < 4; ++i)
                hr[i] = *(const f32x4*)&h_lds[ns][4 * l + 256 * i];
        }
#pragma unroll
        for (int i = 0; i < 4; ++i) xr[i] = xn[i];
    }
}

extern "C" void kernel_launch(void* const* d_in, const int* in_sizes, int n_in,
                              void* d_out, int out_size, void* d_ws, size_t ws_size,
                              hipStream_t stream)
{
    const float* x    = (const float*)d_in[0];
    const float* W_ih = (const float*)d_in[1];
    const float* W_hh = (const float*)d_in[2];
    const float* b_ih = (const float*)d_in[3];
    const float* b_hh = (const float*)d_in[4];
    const float* h0   = (const float*)d_in[5];
    const float* c0   = (const float*)d_in[6];

    unsigned int* ring = (unsigned int*)d_ws;
    hipMemsetAsync(d_ws, 0, 2 * NBLK * 16 * sizeof(unsigned int), stream);
    lstm_persistent<<<NBLK, NTHR, 0, stream>>>(x, W_ih, W_hh, b_ih, b_hh, h0, c0,
                                               (float*)d_out, ring);
}